// Round 9
// baseline (622.254 us; speedup 1.0000x reference)
//
#include <hip/hip_runtime.h>
#include <math.h>

#define BB 16
#define TT 4096
#define DD 1024
#define HH 32
#define TC1 256                 // K1 rows per block
#define NC1 (TT / TC1)          // 16 partial chunks (partials = 2MB, fits XCD L2)
#define TC3 64                  // K3 rows per block
#define NC3 (TT / TC3)          // 64

static constexpr float kEPS = 1e-6f;

typedef float f32x4 __attribute__((ext_vector_type(4)));

// ---------------- K1: masked partial sums over T ----------------
// grid: (NC1, B) = (16,16) = 256 blocks, 256 threads; thread owns 4 consecutive d.
// Normal loads (R8 showed nt loads regressed K1). Partials: [c][b][d], 2MB/plane.
__global__ __launch_bounds__(256) void reduce_kernel(
    const float* __restrict__ zr, const float* __restrict__ zi,
    const float* __restrict__ mask,
    float* __restrict__ partR, float* __restrict__ partI,
    float* __restrict__ cntP) {
  const int c = blockIdx.x;
  const int b = blockIdx.y;
  const int tid = threadIdx.x;
  const int d4 = tid * 4;

  f32x4 accR = (f32x4)(0.f);
  f32x4 accI = (f32x4)(0.f);
  float msum = 0.f;

  const size_t base = ((size_t)b * TT + (size_t)c * TC1) * DD + d4;
  const float* zrp = zr + base;
  const float* zip = zi + base;
  const float* mp = mask + (size_t)b * TT + (size_t)c * TC1;

  #pragma unroll 8
  for (int t = 0; t < TC1; ++t) {
    const float m = mp[t];
    msum += m;
    f32x4 r  = *(const f32x4*)(zrp + (size_t)t * DD);
    f32x4 im = *(const f32x4*)(zip + (size_t)t * DD);
    accR += r * m;
    accI += im * m;
  }

  const size_t po = ((size_t)c * BB + b) * DD + d4;
  *(f32x4*)(partR + po) = accR;
  *(f32x4*)(partI + po) = accI;
  if (tid == 0) cntP[c * BB + b] = msum;
}

// ---- inline per-(b,d) MLP: (Ar, Ai) -> (A_new_r, A_new_i) ----
__device__ __forceinline__ void mlp_one(
    float Ar, float Ai,
    const float* __restrict__ W1m, const float* __restrict__ b1m,
    const float* __restrict__ W2m, const float* __restrict__ b2m,
    const float* __restrict__ W1p, const float* __restrict__ b1p,
    const float* __restrict__ W2p, const float* __restrict__ b2p,
    float msc, float& anr, float& ani) {
  const float mag = sqrtf(Ar * Ar + Ai * Ai);
  const float log_mag = logf(mag + kEPS);
  const float inv_me = 1.0f / (mag + kEPS);
  const float pr = Ar * inv_me;
  const float pi = Ai * inv_me;

  float md = b2m[0];
  #pragma unroll
  for (int j = 0; j < HH; ++j) {
    float h = log_mag * W1m[j] + b1m[j];
    h = 0.5f * h * (1.0f + erff(h * 0.70710678118654752440f));
    md += h * W2m[j];
  }
  const float lmo = log_mag + msc * md;

  float pv0 = b2p[0];
  float pv1 = b2p[1];
  #pragma unroll
  for (int j = 0; j < HH; ++j) {
    float hp = pr * W1p[2 * j] + pi * W1p[2 * j + 1] + b1p[j];
    hp = 0.5f * hp * (1.0f + erff(hp * 0.70710678118654752440f));
    pv0 += hp * W2p[j];       // W2p[0][j]
    pv1 += hp * W2p[HH + j];  // W2p[1][j]
  }
  const float nrm = fmaxf(sqrtf(pv0 * pv0 + pv1 * pv1), 1e-12f);
  const float r_out = expf(lmo);
  anr = r_out * pv0 / nrm;
  ani = r_out * pv1 / nrm;
}

// ---------------- K3: fused (partial-reduce + MLP) prologue + add/store -----
// grid (NC3, B) = (64,16) = 1024 blocks, 256 threads.
// Prologue: each block redundantly reduces the 16 partial chunks for its b
// (128KB/block, L2-hot since partials are 2MB/plane) and computes the MLP for
// its thread's 4 d's. Body: R4's proven backward walk, nt loads, nt stores.
__global__ __launch_bounds__(256) void add_kernel(
    const float* __restrict__ zr, const float* __restrict__ zi,
    const float* __restrict__ partR, const float* __restrict__ partI,
    const float* __restrict__ cntP,
    const float* __restrict__ W1m, const float* __restrict__ b1m,
    const float* __restrict__ W2m, const float* __restrict__ b2m,
    const float* __restrict__ W1p, const float* __restrict__ b1p,
    const float* __restrict__ W2p, const float* __restrict__ b2p,
    const float* __restrict__ mag_scale,
    float* __restrict__ out) {
  const int c = blockIdx.x;
  const int b = blockIdx.y;
  const int tid = threadIdx.x;
  const int d4 = tid * 4;

  // --- prologue: reduce partials for (b, d4..d4+3) ---
  float count = 0.f;
  #pragma unroll
  for (int cc = 0; cc < NC1; ++cc) count += cntP[cc * BB + b];
  count = fmaxf(count, 1.0f);
  const float inv_cnt = 1.0f / count;

  f32x4 sR = (f32x4)(0.f);
  f32x4 sI = (f32x4)(0.f);
  #pragma unroll
  for (int cc = 0; cc < NC1; ++cc) {
    const size_t po = ((size_t)cc * BB + b) * DD + d4;
    sR += *(const f32x4*)(partR + po);
    sI += *(const f32x4*)(partI + po);
  }
  sR *= inv_cnt;
  sI *= inv_cnt;

  const float msc = mag_scale[0];
  f32x4 ar4, ai4;
  #pragma unroll
  for (int e = 0; e < 4; ++e) {
    float anr, ani;
    mlp_one(sR[e], sI[e], W1m, b1m, W2m, b2m, W1p, b1p, W2p, b2p, msc, anr, ani);
    ar4[e] = anr;
    ai4[e] = ani;
  }

  // --- body: R4's streaming add/store ---
  const size_t base = ((size_t)b * TT + (size_t)c * TC3) * DD + d4;
  const float* zrp = zr + base;
  const float* zip = zi + base;
  float* out0 = out + base;
  float* out1 = out + (size_t)BB * TT * DD + base;

  #pragma unroll 8
  for (int t = TC3 - 1; t >= 0; --t) {
    const size_t ro = (size_t)t * DD;
    f32x4 r  = __builtin_nontemporal_load((const f32x4*)(zrp + ro));
    f32x4 im = __builtin_nontemporal_load((const f32x4*)(zip + ro));
    r += ar4;
    im += ai4;
    __builtin_nontemporal_store(r, (f32x4*)(out0 + ro));
    __builtin_nontemporal_store(im, (f32x4*)(out1 + ro));
  }
}

extern "C" void kernel_launch(void* const* d_in, const int* in_sizes, int n_in,
                              void* d_out, int out_size, void* d_ws, size_t ws_size,
                              hipStream_t stream) {
  const float* zr = (const float*)d_in[0];
  const float* zi = (const float*)d_in[1];
  const float* mask = (const float*)d_in[2];
  const float* W1m = (const float*)d_in[3];
  const float* b1m = (const float*)d_in[4];
  const float* W2m = (const float*)d_in[5];
  const float* b2m = (const float*)d_in[6];
  const float* W1p = (const float*)d_in[7];
  const float* b1p = (const float*)d_in[8];
  const float* W2p = (const float*)d_in[9];
  const float* b2p = (const float*)d_in[10];
  const float* mag_scale = (const float*)d_in[11];

  float* ws = (float*)d_ws;
  float* partR = ws;                       // NC1*BB*DD = 262144 (1MB... x4B = 1MB)
  float* partI = ws + NC1 * BB * DD;       // 262144
  float* cntP  = ws + 2 * NC1 * BB * DD;   // NC1*BB = 256

  dim3 g1(NC1, BB);
  reduce_kernel<<<g1, 256, 0, stream>>>(zr, zi, mask, partR, partI, cntP);

  dim3 g3(NC3, BB);
  add_kernel<<<g3, 256, 0, stream>>>(zr, zi, partR, partI, cntP,
                                     W1m, b1m, W2m, b2m, W1p, b1p, W2p, b2p,
                                     mag_scale, (float*)d_out);
}

// Round 10
// 275.613 us; speedup vs baseline: 2.2577x; 2.2577x over previous
//
#include <hip/hip_runtime.h>
#include <math.h>

#define BB 16
#define TT 4096
#define DD 1024
#define HH 32
#define TCHUNK 64
#define NCHUNK (TT / TCHUNK)   // 64

static constexpr float kEPS = 1e-6f;

typedef float f32x4 __attribute__((ext_vector_type(4)));

// ---------------- Kernel 1: masked partial sums over T ----------------
// grid: (NCHUNK, B), 256 threads; thread owns 4 consecutive d (256*4 = D).
// (R4-exact: normal loads)
__global__ __launch_bounds__(256) void reduce_kernel(
    const float* __restrict__ zr, const float* __restrict__ zi,
    const float* __restrict__ mask,
    float* __restrict__ partR, float* __restrict__ partI,
    float* __restrict__ cntP) {
  const int c = blockIdx.x;
  const int b = blockIdx.y;
  const int tid = threadIdx.x;
  const int d4 = tid * 4;

  f32x4 accR = (f32x4)(0.f);
  f32x4 accI = (f32x4)(0.f);
  float msum = 0.f;

  const size_t base = ((size_t)b * TT + (size_t)c * TCHUNK) * DD + d4;
  const float* zrp = zr + base;
  const float* zip = zi + base;
  const float* mp = mask + (size_t)b * TT + (size_t)c * TCHUNK;

  #pragma unroll 8
  for (int t = 0; t < TCHUNK; ++t) {
    const float m = mp[t];
    msum += m;
    f32x4 r  = *(const f32x4*)(zrp + (size_t)t * DD);
    f32x4 im = *(const f32x4*)(zip + (size_t)t * DD);
    accR += r * m;
    accI += im * m;
  }

  const size_t po = ((size_t)c * BB + b) * DD + d4;
  *(f32x4*)(partR + po) = accR;
  *(f32x4*)(partI + po) = accI;
  if (tid == 0) cntP[c * BB + b] = msum;
}

// ---------------- Kernel 2: reduce partials + per-(b,d) MLP ----------------
// (R4-exact: 64 blocks x 256 threads)
__global__ __launch_bounds__(256) void mlp_kernel(
    const float* __restrict__ partR, const float* __restrict__ partI,
    const float* __restrict__ cntP,
    const float* __restrict__ W1m, const float* __restrict__ b1m,
    const float* __restrict__ W2m, const float* __restrict__ b2m,
    const float* __restrict__ W1p, const float* __restrict__ b1p,
    const float* __restrict__ W2p, const float* __restrict__ b2p,
    const float* __restrict__ mag_scale,
    float* __restrict__ anR, float* __restrict__ anI) {
  const int i = blockIdx.x * blockDim.x + threadIdx.x;
  const int b = i >> 10;   // D = 1024
  const int d = i & (DD - 1);

  __shared__ float cntS;
  if (threadIdx.x == 0) {
    float s = 0.f;
    for (int c = 0; c < NCHUNK; ++c) s += cntP[c * BB + b];
    cntS = s;
  }
  __syncthreads();

  float sR = 0.f, sI = 0.f;
  for (int c = 0; c < NCHUNK; ++c) {
    const size_t po = ((size_t)c * BB + b) * DD + d;
    sR += partR[po];
    sI += partI[po];
  }

  const float count = fmaxf(cntS, 1.0f);
  const float Ar = sR / count;
  const float Ai = sI / count;
  const float mag = sqrtf(Ar * Ar + Ai * Ai);
  const float log_mag = logf(mag + kEPS);
  const float inv_me = 1.0f / (mag + kEPS);
  const float pr = Ar * inv_me;
  const float pi = Ai * inv_me;

  float md = b2m[0];
  #pragma unroll
  for (int j = 0; j < HH; ++j) {
    float h = log_mag * W1m[j] + b1m[j];
    h = 0.5f * h * (1.0f + erff(h * 0.70710678118654752440f));
    md += h * W2m[j];
  }
  const float lmo = log_mag + mag_scale[0] * md;

  float pv0 = b2p[0];
  float pv1 = b2p[1];
  #pragma unroll
  for (int j = 0; j < HH; ++j) {
    float hp = pr * W1p[2 * j] + pi * W1p[2 * j + 1] + b1p[j];
    hp = 0.5f * hp * (1.0f + erff(hp * 0.70710678118654752440f));
    pv0 += hp * W2p[j];       // W2p[0][j]
    pv1 += hp * W2p[HH + j];  // W2p[1][j]
  }
  const float nrm = fmaxf(sqrtf(pv0 * pv0 + pv1 * pv1), 1e-12f);
  const float r_out = expf(lmo);
  anR[i] = r_out * pv0 / nrm;
  anI[i] = r_out * pv1 / nrm;
}

// ---------------- Kernel 3: broadcast add, PLANE-SPLIT ----------------
// grid (NCHUNK, B, 2): blockIdx.z picks the plane. Each thread now runs the
// m13 copy shape: ONE nt load stream + ONE nt store stream (was 4 streams).
// Backward walk + nt load + nt store preserved from R4.
__global__ __launch_bounds__(256) void add_kernel(
    const float* __restrict__ zr, const float* __restrict__ zi,
    const float* __restrict__ anR, const float* __restrict__ anI,
    float* __restrict__ out) {
  const int c = blockIdx.x;
  const int b = blockIdx.y;
  const int p = blockIdx.z;
  const int tid = threadIdx.x;
  const int d4 = tid * 4;

  const int o = b * DD + d4;
  const f32x4 a4 = p ? *(const f32x4*)(anI + o) : *(const f32x4*)(anR + o);

  const size_t base = ((size_t)b * TT + (size_t)c * TCHUNK) * DD + d4;
  const float* src = (p ? zi : zr) + base;
  float* dst = out + (size_t)p * BB * TT * DD + base;

  #pragma unroll 8
  for (int t = TCHUNK - 1; t >= 0; --t) {
    const size_t ro = (size_t)t * DD;
    f32x4 v = __builtin_nontemporal_load((const f32x4*)(src + ro));
    v += a4;
    __builtin_nontemporal_store(v, (f32x4*)(dst + ro));
  }
}

extern "C" void kernel_launch(void* const* d_in, const int* in_sizes, int n_in,
                              void* d_out, int out_size, void* d_ws, size_t ws_size,
                              hipStream_t stream) {
  const float* zr = (const float*)d_in[0];
  const float* zi = (const float*)d_in[1];
  const float* mask = (const float*)d_in[2];
  const float* W1m = (const float*)d_in[3];
  const float* b1m = (const float*)d_in[4];
  const float* W2m = (const float*)d_in[5];
  const float* b2m = (const float*)d_in[6];
  const float* W1p = (const float*)d_in[7];
  const float* b1p = (const float*)d_in[8];
  const float* W2p = (const float*)d_in[9];
  const float* b2p = (const float*)d_in[10];
  const float* mag_scale = (const float*)d_in[11];

  float* ws = (float*)d_ws;
  float* partR = ws;                       // NCHUNK*B*D = 1048576
  float* partI = ws + 1048576;             // 1048576
  float* cntP  = ws + 2097152;             // NCHUNK*B = 1024
  float* anR   = ws + 2098176;             // 16384
  float* anI   = ws + 2114560;             // 16384

  dim3 g(NCHUNK, BB);
  reduce_kernel<<<g, 256, 0, stream>>>(zr, zi, mask, partR, partI, cntP);

  mlp_kernel<<<BB * DD / 256, 256, 0, stream>>>(
      partR, partI, cntP, W1m, b1m, W2m, b2m, W1p, b1p, W2p, b2p, mag_scale,
      anR, anI);

  dim3 g3(NCHUNK, BB, 2);
  add_kernel<<<g3, 256, 0, stream>>>(zr, zi, anR, anI, (float*)d_out);
}